// Round 5
// baseline (483.639 us; speedup 1.0000x reference)
//
#include <hip/hip_runtime.h>
#include <stdint.h>

// Square-attack schedule collapse for B=1, C=3, H=224, EPS=0.05, N_QUERIES=5000.
//
// Each step clamps to [x-eps, x+eps] (band width == step size 2*eps), so any
// covering step snaps the pixel to clip(x + sign*eps, 0, 1). Output per pixel =
// rail of the LAST covering step with nonzero per-channel sign; uncovered
// pixels keep the init vertical-stripe value.
//
// RNG: JAX threefry2x32 with jax_threefry_partitionable=True semantics
// (default in modern JAX):
//   fold_in(key, d)        = tf(key, (0, d))                  [unchanged]
//   split(k)               = k1 = tf(k,(0,0)), k2 = tf(k,(0,1))   [foldlike]
//   random_bits(key,32,n)[i] = X0 ^ X1 of tf(key, (0, i))     [per-elem ctr]

#define HH 224
#define NQ 5000
#define NPIX (HH * HH)      // 50176 = 196 * 256
#define EPSF 0.05f

__device__ __forceinline__ void tf2x32(uint32_t k0, uint32_t k1,
                                       uint32_t x0, uint32_t x1,
                                       uint32_t& o0, uint32_t& o1) {
  // JAX threefry2x32: 20 rounds, key schedule [k0, k1, k0^k1^0x1BD11BDA]
  uint32_t ks2 = k0 ^ k1 ^ 0x1BD11BDAu;
  x0 += k0; x1 += k1;
#define TFR(r) { x0 += x1; x1 = (x1 << (r)) | (x1 >> (32 - (r))); x1 ^= x0; }
  TFR(13) TFR(15) TFR(26) TFR(6)
  x0 += k1;  x1 += ks2 + 1u;
  TFR(17) TFR(29) TFR(16) TFR(24)
  x0 += ks2; x1 += k0 + 2u;
  TFR(13) TFR(15) TFR(26) TFR(6)
  x0 += k0;  x1 += k1 + 3u;
  TFR(17) TFR(29) TFR(16) TFR(24)
  x0 += k1;  x1 += ks2 + 4u;
  TFR(13) TFR(15) TFR(26) TFR(6)
  x0 += ks2; x1 += k0 + 5u;
#undef TFR
  o0 = x0; o1 = x1;
}

// sign(2*u - 1) where u = bitcast(0x3f800000 | bits>>9) - 1; exact in f32:
// determined by mantissa vs 0x400000 (u vs 0.5).
__device__ __forceinline__ int sign_from_bits(uint32_t bits) {
  uint32_t mant = bits >> 9;
  return (mant > 0x400000u) ? 1 : ((mant < 0x400000u) ? -1 : 0);
}

__device__ __forceinline__ float u01_from_bits(uint32_t bits) {
  return __uint_as_float(0x3f800000u | (bits >> 9)) - 1.0f;
}

// static schedule: s = round(224*sqrt(p(t))) per _p_selection; verified exactly
__device__ __forceinline__ int s_of(int t) {
  if (t <= 10)   return 200;
  if (t <= 50)   return 142;
  if (t <= 200)  return 100;
  if (t <= 500)  return 71;
  if (t <= 1000) return 50;
  if (t <= 2000) return 35;
  if (t <= 4000) return 25;
  return 18;  // 4000 < t <= 4999
}

// Kernel A: per-step params (vh, s, 3 channel signs) packed into one u32,
// plus the 672 init stripe signs. base key = jax.random.key(1) = (0,1).
__global__ __launch_bounds__(256) void step_params_kernel(uint32_t* __restrict__ sp,
                                                          int8_t* __restrict__ isign) {
  int t = blockIdx.x * 256 + threadIdx.x;
  if (t < NQ) {
    uint32_t f0, f1;
    tf2x32(0u, 1u, 0u, (uint32_t)(t + 1), f0, f1);      // k = fold_in(base, t+1)
    uint32_t a0, a1, b0, b1;
    tf2x32(f0, f1, 0u, 0u, a0, a1);                     // k1 = tf(k, (0,0))
    tf2x32(f0, f1, 0u, 1u, b0, b1);                     // k2 = tf(k, (0,1))
    // scalar uniform: bits = X0 ^ X1 of tf(k1, (0,0))
    uint32_t u0, u1;
    tf2x32(a0, a1, 0u, 0u, u0, u1);
    int s = s_of(t);
    int vh = (int)floorf(u01_from_bits(u0 ^ u1) * (float)(HH - s));
    // channel signs: bits[c] = X0 ^ X1 of tf(k2, (0,c)), c = 0..2
    uint32_t c0, c1;
    tf2x32(b0, b1, 0u, 0u, c0, c1);
    int g0 = sign_from_bits(c0 ^ c1);
    tf2x32(b0, b1, 0u, 1u, c0, c1);
    int g1 = sign_from_bits(c0 ^ c1);
    tf2x32(b0, b1, 0u, 2u, c0, c1);
    int g2 = sign_from_bits(c0 ^ c1);
    sp[t] = (uint32_t)vh | ((uint32_t)s << 8)
          | ((uint32_t)(g0 + 1) << 16) | ((uint32_t)(g1 + 1) << 18)
          | ((uint32_t)(g2 + 1) << 20);
  }
  if (t < 3 * HH) {   // init signs: k0 = fold_in(base, 0); bits[n] = X0^X1 of tf(k0,(0,n))
    uint32_t g0, g1;
    tf2x32(0u, 1u, 0u, 0u, g0, g1);
    uint32_t o0, o1;
    tf2x32(g0, g1, 0u, (uint32_t)t, o0, o1);
    isign[t] = (int8_t)sign_from_bits(o0 ^ o1);
  }
}

// Kernel B: one thread per pixel; scan all steps from LDS, track per-channel
// last nonzero covering sign, emit rail value.
__global__ __launch_bounds__(256) void resolve_kernel(const uint32_t* __restrict__ sp,
                                                      const int8_t* __restrict__ isign,
                                                      const float* __restrict__ x,
                                                      float* __restrict__ out) {
  __shared__ uint32_t lsp[NQ];
  for (int i = threadIdx.x; i < NQ; i += 256) lsp[i] = sp[i];
  __syncthreads();

  int p = blockIdx.x * 256 + threadIdx.x;   // 0..50175
  int pi = p / HH, pj = p % HH;
  int m = min(pi, pj), M = max(pi, pj);

  int s0 = isign[pj];
  int s1 = isign[HH + pj];
  int s2 = isign[2 * HH + pj];

#pragma unroll 4
  for (int t = 0; t < NQ; ++t) {
    uint32_t w = lsp[t];                    // uniform address -> LDS broadcast
    int vh = (int)(w & 255u);
    int sz = (int)((w >> 8) & 255u);
    bool cov = (vh <= m) & (M < vh + sz);   // diagonal square coverage
    int g0 = (int)((w >> 16) & 3u) - 1;
    int g1 = (int)((w >> 18) & 3u) - 1;
    int g2 = (int)((w >> 20) & 3u) - 1;
    s0 = (cov && g0 != 0) ? g0 : s0;
    s1 = (cov && g1 != 0) ? g1 : s1;
    s2 = (cov && g2 != 0) ? g2 : s2;
  }

  float x0 = x[p];
  float x1 = x[NPIX + p];
  float x2 = x[2 * NPIX + p];
  out[p]            = (s0 > 0) ? fminf(x0 + EPSF, 1.0f)
                    : (s0 < 0) ? fmaxf(x0 - EPSF, 0.0f)
                               : fminf(fmaxf(x0, 0.0f), 1.0f);
  out[NPIX + p]     = (s1 > 0) ? fminf(x1 + EPSF, 1.0f)
                    : (s1 < 0) ? fmaxf(x1 - EPSF, 0.0f)
                               : fminf(fmaxf(x1, 0.0f), 1.0f);
  out[2 * NPIX + p] = (s2 > 0) ? fminf(x2 + EPSF, 1.0f)
                    : (s2 < 0) ? fmaxf(x2 - EPSF, 0.0f)
                               : fminf(fmaxf(x2, 0.0f), 1.0f);
}

extern "C" void kernel_launch(void* const* d_in, const int* in_sizes, int n_in,
                              void* d_out, int out_size, void* d_ws, size_t ws_size,
                              hipStream_t stream) {
  const float* x = (const float*)d_in[0];
  float* out = (float*)d_out;
  uint32_t* sp = (uint32_t*)d_ws;                    // 5000 * 4 = 20000 B
  int8_t* isign = (int8_t*)d_ws + NQ * 4;            // 672 B

  step_params_kernel<<<(NQ + 255) / 256, 256, 0, stream>>>(sp, isign);
  resolve_kernel<<<NPIX / 256, 256, 0, stream>>>(sp, isign, x, out);
}

// Round 8
// 71.439 us; speedup vs baseline: 6.7700x; 6.7700x over previous
//
#include <hip/hip_runtime.h>
#include <stdint.h>

// Square-attack schedule collapse for B=1, C=3, H=224, EPS=0.05, N_QUERIES=5000.
//
// R5: PASS (absmax 0.0) with linear 5000-step scan; resolve was latency-bound
// (442 us, VALUBusy 13%, occupancy 9%). R6: replace the scan with per-segment
// sparse range-max tables: 8 static s-segments; within a segment, step t
// covers pixel (m=min(i,j), M=max(i,j)) iff vh_t in [M-s+1, m] (clamped).
// Bin by vh keeping max of ((t+1)<<1 | sign>0) per (seg, channel); sparse
// table gives O(1) range-max. Global-t encoding makes cross-segment combine a
// plain max. 48 independent LDS u16 loads per pixel instead of 5000 iters.
//
// RNG: JAX threefry2x32, jax_threefry_partitionable=True (verified exact):
//   fold_in(key, d)          = tf(key, (0, d))
//   split(k)                 = k1 = tf(k,(0,0)), k2 = tf(k,(0,1))
//   random_bits(key,32,n)[i] = X0 ^ X1 of tf(key, (0, i))

#define HH 224
#define NQ 5000
#define NPIX (HH * HH)      // 50176 = 196 * 256
#define EPSF 0.05f
#define NTAB (8 * 3 * 8 * 224)   // [seg][c][k][v] u16 = 43008 elems = 86016 B

__device__ __forceinline__ void tf2x32(uint32_t k0, uint32_t k1,
                                       uint32_t x0, uint32_t x1,
                                       uint32_t& o0, uint32_t& o1) {
  uint32_t ks2 = k0 ^ k1 ^ 0x1BD11BDAu;
  x0 += k0; x1 += k1;
#define TFR(r) { x0 += x1; x1 = (x1 << (r)) | (x1 >> (32 - (r))); x1 ^= x0; }
  TFR(13) TFR(15) TFR(26) TFR(6)
  x0 += k1;  x1 += ks2 + 1u;
  TFR(17) TFR(29) TFR(16) TFR(24)
  x0 += ks2; x1 += k0 + 2u;
  TFR(13) TFR(15) TFR(26) TFR(6)
  x0 += k0;  x1 += k1 + 3u;
  TFR(17) TFR(29) TFR(16) TFR(24)
  x0 += k1;  x1 += ks2 + 4u;
  TFR(13) TFR(15) TFR(26) TFR(6)
  x0 += ks2; x1 += k0 + 5u;
#undef TFR
  o0 = x0; o1 = x1;
}

__device__ __forceinline__ int sign_from_bits(uint32_t bits) {
  uint32_t mant = bits >> 9;
  return (mant > 0x400000u) ? 1 : ((mant < 0x400000u) ? -1 : 0);
}

__device__ __forceinline__ float u01_from_bits(uint32_t bits) {
  return __uint_as_float(0x3f800000u | (bits >> 9)) - 1.0f;
}

// static schedule: s = round(224*sqrt(p(t))) per _p_selection; verified exact
__device__ __forceinline__ int s_of(int t) {
  if (t <= 10)   return 200;
  if (t <= 50)   return 142;
  if (t <= 200)  return 100;
  if (t <= 500)  return 71;
  if (t <= 1000) return 50;
  if (t <= 2000) return 35;
  if (t <= 4000) return 25;
  return 18;
}

__device__ __forceinline__ int seg_of(int t) {
  if (t <= 10)   return 0;
  if (t <= 50)   return 1;
  if (t <= 200)  return 2;
  if (t <= 500)  return 3;
  if (t <= 1000) return 4;
  if (t <= 2000) return 5;
  if (t <= 4000) return 6;
  return 7;
}

// --- Kernel A1: per-step params packed into u32, plus 672 init stripe signs.
__global__ __launch_bounds__(256) void step_params_kernel(uint32_t* __restrict__ sp,
                                                          int8_t* __restrict__ isign) {
  int t = blockIdx.x * 256 + threadIdx.x;
  if (t < NQ) {
    uint32_t f0, f1;
    tf2x32(0u, 1u, 0u, (uint32_t)(t + 1), f0, f1);      // k = fold_in(base, t+1)
    uint32_t a0, a1, b0, b1;
    tf2x32(f0, f1, 0u, 0u, a0, a1);                     // k1 = tf(k, (0,0))
    tf2x32(f0, f1, 0u, 1u, b0, b1);                     // k2 = tf(k, (0,1))
    uint32_t u0, u1;
    tf2x32(a0, a1, 0u, 0u, u0, u1);                     // scalar uniform bits
    int s = s_of(t);
    int vh = (int)floorf(u01_from_bits(u0 ^ u1) * (float)(HH - s));
    uint32_t c0, c1;
    tf2x32(b0, b1, 0u, 0u, c0, c1);
    int g0 = sign_from_bits(c0 ^ c1);
    tf2x32(b0, b1, 0u, 1u, c0, c1);
    int g1 = sign_from_bits(c0 ^ c1);
    tf2x32(b0, b1, 0u, 2u, c0, c1);
    int g2 = sign_from_bits(c0 ^ c1);
    sp[t] = (uint32_t)vh | ((uint32_t)s << 8)
          | ((uint32_t)(g0 + 1) << 16) | ((uint32_t)(g1 + 1) << 18)
          | ((uint32_t)(g2 + 1) << 20);
  }
  if (t < 3 * HH) {
    uint32_t g0, g1;
    tf2x32(0u, 1u, 0u, 0u, g0, g1);                     // fold_in(base, 0)
    uint32_t o0, o1;
    tf2x32(g0, g1, 0u, (uint32_t)t, o0, o1);
    isign[t] = (int8_t)sign_from_bits(o0 ^ o1);
  }
}

// --- Kernel A2: bin steps by vh per (seg, chan); build sparse range-max
// tables; write 86 KB table to global. Single block, 1024 threads.
__global__ __launch_bounds__(1024) void table_build_kernel(const uint32_t* __restrict__ sp,
                                                           uint16_t* __restrict__ gtab) {
  __shared__ uint32_t bins[8 * 3 * 224];   // [seg][c][v]
  __shared__ uint16_t tab[NTAB];           // [(seg*3+c)*8 + k][v]
  int tid = threadIdx.x;
  for (int i = tid; i < 8 * 3 * 224; i += 1024) bins[i] = 0;
  __syncthreads();
  for (int t = tid; t < NQ; t += 1024) {
    uint32_t w = sp[t];
    int vh = (int)(w & 255u);
    int base = seg_of(t) * 3 * 224;
    uint32_t val = ((uint32_t)(t + 1)) << 1;
    int g0 = (int)((w >> 16) & 3u) - 1;
    int g1 = (int)((w >> 18) & 3u) - 1;
    int g2 = (int)((w >> 20) & 3u) - 1;
    if (g0) atomicMax(&bins[base + vh],       val | (uint32_t)(g0 > 0));
    if (g1) atomicMax(&bins[base + 224 + vh], val | (uint32_t)(g1 > 0));
    if (g2) atomicMax(&bins[base + 448 + vh], val | (uint32_t)(g2 > 0));
  }
  __syncthreads();
  for (int i = tid; i < 8 * 3 * 224; i += 1024) {   // level 0
    int sc = i / 224, v = i % 224;
    tab[(sc * 8) * 224 + v] = (uint16_t)bins[i];
  }
  __syncthreads();
  for (int k = 1; k < 8; ++k) {
    int w = 1 << (k - 1);
    for (int i = tid; i < 8 * 3 * 224; i += 1024) {
      int sc = i / 224, v = i % 224;
      uint16_t a = tab[(sc * 8 + k - 1) * 224 + v];
      uint16_t b = (v + w < 224) ? tab[(sc * 8 + k - 1) * 224 + v + w] : (uint16_t)0;
      tab[(sc * 8 + k) * 224 + v] = (a > b) ? a : b;
    }
    __syncthreads();
  }
  const uint32_t* t32 = (const uint32_t*)tab;
  uint32_t* g32 = (uint32_t*)gtab;
  for (int i = tid; i < NTAB / 2; i += 1024) g32[i] = t32[i];
}

// --- Kernel B: stage table to LDS; per pixel, 8 O(1) range-max queries per
// channel (48 independent u16 LDS loads); emit rail value.
__global__ __launch_bounds__(256) void resolve_kernel(const uint16_t* __restrict__ gtab,
                                                      const int8_t* __restrict__ isign,
                                                      const float* __restrict__ x,
                                                      float* __restrict__ out) {
  __shared__ uint16_t tab[NTAB];           // 86016 B
  {
    float4* t4 = (float4*)tab;
    const float4* g4 = (const float4*)gtab;
    for (int i = threadIdx.x; i < NTAB * 2 / 16; i += 256) t4[i] = g4[i];
  }
  __syncthreads();

  int p = blockIdx.x * 256 + threadIdx.x;   // 0..50175
  int pi = p / HH, pj = p % HH;
  int m = min(pi, pj), M = max(pi, pj);

  const int SEG_S[8] = {200, 142, 100, 71, 50, 35, 25, 18};
  uint32_t best0 = 0, best1 = 0, best2 = 0;
#pragma unroll
  for (int seg = 0; seg < 8; ++seg) {
    const int s = SEG_S[seg];
    int lo = max(0, M - s + 1);
    int hi = min(m, 223 - s);
    bool ok = (lo <= hi);
    int len = ok ? (hi - lo + 1) : 1;
    int k = 31 - __clz(len);
    int o2 = hi + 1 - (1 << k);             // >= lo >= 0 when ok; == hi when !ok
    int b = seg * 5376 + k * 224;           // c stride = 8*224 = 1792
    uint32_t v0 = max((uint32_t)tab[b + lo],        (uint32_t)tab[b + o2]);
    uint32_t v1 = max((uint32_t)tab[b + 1792 + lo], (uint32_t)tab[b + 1792 + o2]);
    uint32_t v2 = max((uint32_t)tab[b + 3584 + lo], (uint32_t)tab[b + 3584 + o2]);
    if (!ok) { v0 = 0u; v1 = 0u; v2 = 0u; }
    best0 = max(best0, v0);
    best1 = max(best1, v1);
    best2 = max(best2, v2);
  }

  int s0 = best0 ? ((best0 & 1u) ? 1 : -1) : (int)isign[pj];
  int s1 = best1 ? ((best1 & 1u) ? 1 : -1) : (int)isign[HH + pj];
  int s2 = best2 ? ((best2 & 1u) ? 1 : -1) : (int)isign[2 * HH + pj];

  float x0 = x[p];
  float x1 = x[NPIX + p];
  float x2 = x[2 * NPIX + p];
  out[p]            = (s0 > 0) ? fminf(x0 + EPSF, 1.0f)
                    : (s0 < 0) ? fmaxf(x0 - EPSF, 0.0f)
                               : fminf(fmaxf(x0, 0.0f), 1.0f);
  out[NPIX + p]     = (s1 > 0) ? fminf(x1 + EPSF, 1.0f)
                    : (s1 < 0) ? fmaxf(x1 - EPSF, 0.0f)
                               : fminf(fmaxf(x1, 0.0f), 1.0f);
  out[2 * NPIX + p] = (s2 > 0) ? fminf(x2 + EPSF, 1.0f)
                    : (s2 < 0) ? fmaxf(x2 - EPSF, 0.0f)
                               : fminf(fmaxf(x2, 0.0f), 1.0f);
}

extern "C" void kernel_launch(void* const* d_in, const int* in_sizes, int n_in,
                              void* d_out, int out_size, void* d_ws, size_t ws_size,
                              hipStream_t stream) {
  const float* x = (const float*)d_in[0];
  float* out = (float*)d_out;
  uint32_t* sp = (uint32_t*)d_ws;                            // [0, 20000)
  int8_t* isign = (int8_t*)d_ws + NQ * 4;                    // [20000, 20672)
  uint16_t* gtab = (uint16_t*)((char*)d_ws + 20672);         // 16-aligned, 86016 B

  step_params_kernel<<<(NQ + 255) / 256, 256, 0, stream>>>(sp, isign);
  table_build_kernel<<<1, 1024, 0, stream>>>(sp, gtab);
  resolve_kernel<<<NPIX / 256, 256, 0, stream>>>(gtab, isign, x, out);
}